// Round 5
// baseline (257.491 us; speedup 1.0000x reference)
//
#include <hip/hip_runtime.h>
#include <hip/hip_bf16.h>
#include <math.h>

#define N_   16
#define CIN  16
#define D_   32
#define H_   64
#define W_   64
#define COUT 32

#define DHW_ (D_ * H_ * W_)
#define HW_  (H_ * W_)

using frag  = __attribute__((ext_vector_type(8))) short;   // 8 bf16 = 4 VGPRs
using v16f  = __attribute__((ext_vector_type(16))) float;  // MFMA 32x32 accum

static __device__ __forceinline__ unsigned short f2bf(float f) {
  union { float f; unsigned u; } a; a.f = f;
  unsigned u = a.u;
  unsigned r = (u + 0x7fffu + ((u >> 16) & 1u)) >> 16;   // RNE
  return (unsigned short)r;
}
static __device__ __forceinline__ unsigned pack2(float lo, float hi) {
  return (unsigned)f2bf(lo) | ((unsigned)f2bf(hi) << 16);
}

// ---- Pass 1: weights fp32 [oc][ic][tap] -> bf16 [tap][oc][ic] ----------------
__global__ __launch_bounds__(256)
void prep_w(const float* __restrict__ w, __hip_bfloat16* __restrict__ wT) {
  int i = blockIdx.x * 256 + threadIdx.x;
  if (i >= 27 * 32 * 16) return;
  int ic = i & 15, t = i >> 4, oc = t & 31, tap = t >> 5;
  wT[i] = __hip_bfloat16(__hip_bfloat16_raw{f2bf(w[(oc * 16 + ic) * 27 + tap])});
}

// ---- Pass 2: one block per (wt, hpt, n, dp) ----------------------------------
// Block = 4 waves. Stage 4 d-planes once -> ONE barrier -> 108 MFMA/wave ->
// pool+LSE epilogue -> exit. Inter-block co-residency (2 blocks/CU, 16
// blocks/CU total) provides the stage/compute overlap; no intra-kernel
// pipeline. All staging loads hoisted into registers before any LDS write
// (single MLP burst instead of chained round-trips).
__global__ __launch_bounds__(256, 2)
void conv_once(const float* __restrict__ x,
               const __hip_bfloat16* __restrict__ wT,
               const float* __restrict__ w,
               const int use_wt,
               const float* __restrict__ bias,
               float* __restrict__ out) {
  __shared__ __hip_bfloat16 xlds[4 * 10 * 34 * 16];   // 43520 B
  __shared__ __hip_bfloat16 wlds[27 * 32 * 16];       // 27648 B

  const int tid = threadIdx.x;
  const int lane = tid & 63;
  const int q = tid >> 6;            // wave id
  const int m = lane & 31;
  const int hs = lane >> 5;
  const int wt = blockIdx.x;         // 0..1
  const int hpt = blockIdx.y;        // 0..7
  const int dp = blockIdx.z & 15;
  const int n = blockIdx.z >> 4;

  // ---- stage weights ---------------------------------------------------------
  if (use_wt) {
    // dense async copy of pre-converted bf16 [tap][oc][ic]: 27 KiB chunks
    for (int c = q; c < 27; c += 4) {
      __builtin_amdgcn_global_load_lds(
          (const __attribute__((address_space(1))) void*)
              ((const char*)wT + c * 1024 + lane * 16),
          (__attribute__((address_space(3))) void*)((char*)wlds + c * 1024),
          16, 0, 0);
    }
  } else {
    for (int i = tid; i < 27 * 32 * 16; i += 256) {
      int ic = i & 15, t2 = i >> 4, oc = t2 & 31, tap = t2 >> 5;
      wlds[i] = __hip_bfloat16(__hip_bfloat16_raw{f2bf(w[(oc * 16 + ic) * 27 + tap])});
    }
  }

  const float bv = bias[m];
  const int abase = m * 16 + hs * 8;
  const int h0 = 8 * hpt - 1;
  const int w0g = wt * 32 - 1;
  const float* xn = x + (size_t)n * CIN * DHW_;

  // ---- stage x: 2720 tasks = 4 planes x 10 rows x 34 w-slots x 2 ic-halves ---
  // Phase 1: issue ALL global loads (deep MLP). Phase 2: pack+ds_write.
  float f[11][8];
  #pragma unroll
  for (int k = 0; k < 11; ++k) {
    int t = tid + 256 * k;
    if (t < 2720) {
      int ru = t / 68;
      int sub = t - ru * 68;
      int j = ru / 10;             // plane offset 0..3
      int rr = ru - j * 10;        // row 0..9
      int s = sub >> 1;            // w-slot 0..33
      int half = sub & 1;          // ic half
      int g = 2 * dp - 1 + j;
      int h = h0 + rr, gw = w0g + s;
      bool v = ((unsigned)g < (unsigned)D_) && ((unsigned)h < (unsigned)H_) &&
               ((unsigned)gw < (unsigned)W_);
      const float* p = xn + (size_t)(half * 8) * DHW_ + g * HW_ + h * W_ + gw;
      #pragma unroll
      for (int jj = 0; jj < 8; ++jj) f[k][jj] = v ? p[(size_t)jj * DHW_] : 0.f;
    }
  }
  #pragma unroll
  for (int k = 0; k < 11; ++k) {
    int t = tid + 256 * k;
    if (t < 2720) {
      int ru = t / 68;
      int sub = t - ru * 68;
      int j = ru / 10;
      int rr = ru - j * 10;
      int s = sub >> 1;
      int half = sub & 1;
      uint4 val;
      val.x = pack2(f[k][0], f[k][1]); val.y = pack2(f[k][2], f[k][3]);
      val.z = pack2(f[k][4], f[k][5]); val.w = pack2(f[k][6], f[k][7]);
      *(uint4*)&xlds[(((j * 10 + rr) * 34 + s) * 16) + half * 8] = val;
    }
  }

  __syncthreads();   // staging + weight copy visible

  // ---- 108 MFMAs/wave (verified structure) -----------------------------------
  v16f acc[2][2];
  #pragma unroll
  for (int td = 0; td < 2; ++td)
    #pragma unroll
    for (int th = 0; th < 2; ++th)
      #pragma unroll
      for (int e = 0; e < 16; ++e) acc[td][th][e] = 0.f;

  #pragma unroll
  for (int kw = 0; kw < 3; ++kw) {
    frag a[4][4];   // [plane j = kd+td][row r = kh+th], rows 2q..2q+3
    #pragma unroll
    for (int j = 0; j < 4; ++j)
      #pragma unroll
      for (int r = 0; r < 4; ++r)
        a[j][r] = *(const frag*)&xlds[((j * 10 + 2 * q + r) * 34 + kw) * 16 + abase];
    #pragma unroll
    for (int kd = 0; kd < 3; ++kd)
      #pragma unroll
      for (int kh = 0; kh < 3; ++kh) {
        frag b = *(const frag*)&wlds[((kd * 3 + kh) * 3 + kw) * 512 + abase];
        #pragma unroll
        for (int td = 0; td < 2; ++td)
          #pragma unroll
          for (int th = 0; th < 2; ++th)
            acc[td][th] = __builtin_amdgcn_mfma_f32_32x32x16_bf16(
                a[kd + td][kh + th], b, acc[td][th], 0, 0, 0);
      }
  }

  // ---- pool (2x2x2) + bias + LSE over oc + relu + store ----------------------
  #pragma unroll
  for (int j = 0; j < 8; ++j) {
    float p0 = fmaxf(fmaxf(acc[0][0][2 * j], acc[0][0][2 * j + 1]),
                     fmaxf(acc[0][1][2 * j], acc[0][1][2 * j + 1]));
    float p1 = fmaxf(fmaxf(acc[1][0][2 * j], acc[1][0][2 * j + 1]),
                     fmaxf(acc[1][1][2 * j], acc[1][1][2 * j + 1]));
    float v = fmaxf(p0, p1) + bv;
    float M = v;
    #pragma unroll
    for (int s = 16; s >= 1; s >>= 1) M = fmaxf(M, __shfl_xor(M, s, 64));
    float S = __expf(v - M);
    #pragma unroll
    for (int s = 16; s >= 1; s >>= 1) S += __shfl_xor(S, s, 64);
    if (m == 0) {
      float r = fmaxf(M + __logf(S), 0.f);
      int pw = 16 * wt + (j & 1) + 4 * (j >> 1) + 2 * hs;
      out[((n * 16 + dp) * 32 + 4 * hpt + q) * 32 + pw] = r;
    }
  }
}

extern "C" void kernel_launch(void* const* d_in, const int* in_sizes, int n_in,
                              void* d_out, int out_size, void* d_ws, size_t ws_size,
                              hipStream_t stream) {
  const float* x = (const float*)d_in[0];
  const float* w = (const float*)d_in[1];
  const float* b = (const float*)d_in[2];
  float* out = (float*)d_out;
  const size_t needW = (size_t)27 * 32 * 16 * 2;   // 27648 B
  if (ws_size >= needW) {
    __hip_bfloat16* wT = (__hip_bfloat16*)d_ws;
    prep_w<<<dim3(54), dim3(256), 0, stream>>>(w, wT);
    conv_once<<<dim3(2, 8, 256), dim3(256), 0, stream>>>(x, wT, w, 1, b, out);
  } else {
    conv_once<<<dim3(2, 8, 256), dim3(256), 0, stream>>>(x, nullptr, w, 0, b, out);
  }
}

// Round 6
// 246.474 us; speedup vs baseline: 1.0447x; 1.0447x over previous
//
#include <hip/hip_runtime.h>
#include <hip/hip_bf16.h>
#include <math.h>

#define N_   16
#define CIN  16
#define D_   32
#define H_   64
#define W_   64

#define DHW_ (D_ * H_ * W_)
#define HW_  (H_ * W_)

#define RING 6      // d-plane ring slots
#define ROWS 18     // conv-h rows incl halo (8 pooled-h)
#define WS   34     // w slots incl halo (32 conv-w)
#define XROW (WS * 16)        // 544 elems per (slot,row)
#define XPLANE (ROWS * XROW)  // 9792 elems per ring slot

using frag  = __attribute__((ext_vector_type(8))) short;   // 8 bf16 = 4 VGPRs
using v16f  = __attribute__((ext_vector_type(16))) float;  // MFMA 32x32 accum

static __device__ __forceinline__ unsigned short f2bf(float f) {
  union { float f; unsigned u; } a; a.f = f;
  unsigned u = a.u;
  unsigned r = (u + 0x7fffu + ((u >> 16) & 1u)) >> 16;   // RNE
  return (unsigned short)r;
}
static __device__ __forceinline__ unsigned pack2(float lo, float hi) {
  return (unsigned)f2bf(lo) | ((unsigned)f2bf(hi) << 16);
}

// Persistent-ish block: one block per CU (grid=256, 512 thr = 8 waves).
// Block covers (wt: 32 conv-w, hpt: 8 pooled-h, n, dp-half: 8 dp).
// xlds = ring of 6 d-plane slots; per dpi only 2 new planes gathered from
// fp32 x (burst loads issued BEFORE the MFMA block; packed+written after —
// 3456 cycles of MFMA hide the L3 latency; barrier drains nothing).
// XOR bank swizzle on the 16B ic-half chunk kills the 8-way LDS conflicts.
__global__ __launch_bounds__(512, 2)
void conv_ring(const float* __restrict__ x,
               const float* __restrict__ w,
               const float* __restrict__ bias,
               float* __restrict__ out) {
  __shared__ __hip_bfloat16 xlds[RING * XPLANE];   // 117504 B
  __shared__ __hip_bfloat16 wlds[27 * 32 * 16];    // 27648 B

  const int tid = threadIdx.x;
  const int lane = tid & 63;
  const int q = tid >> 6;            // wave id = pooled-h within tile (0..7)
  const int m = lane & 31;
  const int hs = lane >> 5;
  const int wt = blockIdx.x;         // 0..1
  const int hpt = blockIdx.y;        // 0..3
  const int n = blockIdx.z >> 1;
  const int dp0 = (blockIdx.z & 1) * 8;

  // ---- stage weights once: wlds[tap][oc][ic] (swizzled ic-half) -------------
  for (int i = tid; i < 27 * 32 * 16; i += 512) {
    int ic = i & 15, t2 = i >> 4, oc = t2 & 31, tap = t2 >> 5;
    int dst = (tap * 32 + oc) * 16 + ((((ic >> 3) ^ ((oc >> 2) & 1))) << 3) + (ic & 7);
    wlds[dst] = __hip_bfloat16(__hip_bfloat16_raw{f2bf(w[(oc * 16 + ic) * 27 + tap])});
  }

  const float bv = bias[m];
  const int h0 = 16 * hpt - 1;
  const int w0g = wt * 32 - 1;
  const float* xn = x + (size_t)n * CIN * DHW_;

  // task decode: ru=t/68 -> (plane pl, row rr); sub=t%68 -> (w-slot s, ic-half)
  // LDS elem addr for (slot,rr,s,half): ((slot*ROWS+rr)*WS+s)*16 + swz(half,s)*8
  // ---- prologue: stage 4 planes (2*dp0-1 .. 2*dp0+2), 4896 tasks ------------
  {
    float f[10][8];
    #pragma unroll
    for (int k = 0; k < 10; ++k) {
      int t = tid + 512 * k;
      if (t < 4896) {
        int ru = t / 68, sub = t - ru * 68;
        int pl = ru / 18, rr = ru - pl * 18;
        int s = sub >> 1, half = sub & 1;
        int g = 2 * dp0 - 1 + pl;
        int h = h0 + rr, gw = w0g + s;
        bool v = ((unsigned)g < (unsigned)D_) && ((unsigned)h < (unsigned)H_) &&
                 ((unsigned)gw < (unsigned)W_);
        const float* p = xn + (size_t)(half * 8) * DHW_ + g * HW_ + h * W_ + gw;
        #pragma unroll
        for (int j = 0; j < 8; ++j) f[k][j] = v ? p[(size_t)j * DHW_] : 0.f;
      }
    }
    #pragma unroll
    for (int k = 0; k < 10; ++k) {
      int t = tid + 512 * k;
      if (t < 4896) {
        int ru = t / 68, sub = t - ru * 68;
        int pl = ru / 18, rr = ru - pl * 18;
        int s = sub >> 1, half = sub & 1;
        int g = 2 * dp0 - 1 + pl;
        int slot = (g + 12) % 6;
        uint4 val;
        val.x = pack2(f[k][0], f[k][1]); val.y = pack2(f[k][2], f[k][3]);
        val.z = pack2(f[k][4], f[k][5]); val.w = pack2(f[k][6], f[k][7]);
        int dst = ((slot * ROWS + rr) * WS + s) * 16 +
                  ((half ^ ((s >> 2) & 1)) << 3);
        *(uint4*)&xlds[dst] = val;
      }
    }
  }
  __syncthreads();

  // per-lane hoisted LDS offsets (swizzled)
  int axoff[3];
  #pragma unroll
  for (int kw = 0; kw < 3; ++kw) {
    int s = kw + m;
    axoff[kw] = s * 16 + ((hs ^ ((s >> 2) & 1)) << 3);
  }
  const int boff = m * 16 + ((hs ^ ((m >> 2) & 1)) << 3);

  for (int dpi = 0; dpi < 8; ++dpi) {
    const int dp = dp0 + dpi;

    // ---- 1. issue gather loads for next plane pair (2dp+3, 2dp+4) ----------
    float pf[5][8];
    if (dpi < 7) {
      #pragma unroll
      for (int k = 0; k < 5; ++k) {
        int t = tid + 512 * k;
        if (t < 2448) {
          int ru = t / 68, sub = t - ru * 68;
          int pl = ru >= 18 ? 1 : 0, rr = ru - 18 * pl;
          int s = sub >> 1, half = sub & 1;
          int g = 2 * dp + 3 + pl;
          int h = h0 + rr, gw = w0g + s;
          bool v = ((unsigned)g < (unsigned)D_) && ((unsigned)h < (unsigned)H_) &&
                   ((unsigned)gw < (unsigned)W_);
          const float* p = xn + (size_t)(half * 8) * DHW_ + g * HW_ + h * W_ + gw;
          #pragma unroll
          for (int j = 0; j < 8; ++j) pf[k][j] = v ? p[(size_t)j * DHW_] : 0.f;
        }
      }
    }

    // ---- 2. MFMA: 108 per wave (verified structure) ------------------------
    v16f acc[2][2];
    #pragma unroll
    for (int td = 0; td < 2; ++td)
      #pragma unroll
      for (int th = 0; th < 2; ++th)
        #pragma unroll
        for (int e = 0; e < 16; ++e) acc[td][th][e] = 0.f;

    int sj[4];
    #pragma unroll
    for (int j = 0; j < 4; ++j) sj[j] = (2 * dp - 1 + j + 12) % 6;

    #pragma unroll
    for (int kw = 0; kw < 3; ++kw) {
      frag a[4][4];   // [plane j = kd+td][row r = kh+th], rows 2q..2q+3
      #pragma unroll
      for (int j = 0; j < 4; ++j)
        #pragma unroll
        for (int r = 0; r < 4; ++r)
          a[j][r] = *(const frag*)&xlds[(sj[j] * ROWS + 2 * q + r) * XROW + axoff[kw]];
      #pragma unroll
      for (int kd = 0; kd < 3; ++kd)
        #pragma unroll
        for (int kh = 0; kh < 3; ++kh) {
          frag b = *(const frag*)&wlds[((kd * 3 + kh) * 3 + kw) * 512 + boff];
          #pragma unroll
          for (int td = 0; td < 2; ++td)
            #pragma unroll
            for (int th = 0; th < 2; ++th)
              acc[td][th] = __builtin_amdgcn_mfma_f32_32x32x16_bf16(
                  a[kd + td][kh + th], b, acc[td][th], 0, 0, 0);
        }
    }

    // ---- 3. commit next pair to ring slots (loads long since landed) -------
    if (dpi < 7) {
      #pragma unroll
      for (int k = 0; k < 5; ++k) {
        int t = tid + 512 * k;
        if (t < 2448) {
          int ru = t / 68, sub = t - ru * 68;
          int pl = ru >= 18 ? 1 : 0, rr = ru - 18 * pl;
          int s = sub >> 1, half = sub & 1;
          int g = 2 * dp + 3 + pl;
          int slot = (g + 12) % 6;
          uint4 val;
          val.x = pack2(pf[k][0], pf[k][1]); val.y = pack2(pf[k][2], pf[k][3]);
          val.z = pack2(pf[k][4], pf[k][5]); val.w = pack2(pf[k][6], pf[k][7]);
          int dst = ((slot * ROWS + rr) * WS + s) * 16 +
                    ((half ^ ((s >> 2) & 1)) << 3);
          *(uint4*)&xlds[dst] = val;
        }
      }
    }

    // ---- 4. pool (2x2x2) + bias + LSE over oc + relu + store ---------------
    #pragma unroll
    for (int j = 0; j < 8; ++j) {
      float p0 = fmaxf(fmaxf(acc[0][0][2 * j], acc[0][0][2 * j + 1]),
                       fmaxf(acc[0][1][2 * j], acc[0][1][2 * j + 1]));
      float p1 = fmaxf(fmaxf(acc[1][0][2 * j], acc[1][0][2 * j + 1]),
                       fmaxf(acc[1][1][2 * j], acc[1][1][2 * j + 1]));
      float v = fmaxf(p0, p1) + bv;
      float M = v;
      #pragma unroll
      for (int s = 16; s >= 1; s >>= 1) M = fmaxf(M, __shfl_xor(M, s, 64));
      float S = __expf(v - M);
      #pragma unroll
      for (int s = 16; s >= 1; s >>= 1) S += __shfl_xor(S, s, 64);
      if (m == 0) {
        float r = fmaxf(M + __logf(S), 0.f);
        int pw = 16 * wt + (j & 1) + 4 * (j >> 1) + 2 * hs;
        out[((n * 16 + dp) * 32 + 8 * hpt + q) * 32 + pw] = r;
      }
    }

    __syncthreads();   // dpi+1's planes visible; dpi's slot reads finished
  }
}

extern "C" void kernel_launch(void* const* d_in, const int* in_sizes, int n_in,
                              void* d_out, int out_size, void* d_ws, size_t ws_size,
                              hipStream_t stream) {
  const float* x = (const float*)d_in[0];
  const float* w = (const float*)d_in[1];
  const float* b = (const float*)d_in[2];
  float* out = (float*)d_out;
  conv_ring<<<dim3(2, 4, 32), dim3(512), 0, stream>>>(x, w, b, out);
}